// Round 2
// baseline (5492.176 us; speedup 1.0000x reference)
//
#include <hip/hip_runtime.h>

#define KAPPA 0.99f

// ---------- Projection of each row of W onto the L1 ball of radius KAPPA ----------
// one block (64 threads) per row; bitonic sort of |w| then exact threshold.
__global__ __launch_bounds__(64) void proj_kernel(const float* __restrict__ W,
                                                  float* __restrict__ WpT) {
  __shared__ float a[128];
  __shared__ float css[128];
  __shared__ float s_alpha, s_l1;
  int row = blockIdx.x;
  int t = threadIdx.x;
  a[t]      = fabsf(W[row * 128 + t]);
  a[t + 64] = fabsf(W[row * 128 + t + 64]);
  __syncthreads();
  // bitonic ascending sort, 128 elements, 64 threads
  for (int k = 2; k <= 128; k <<= 1) {
    for (int j = k >> 1; j > 0; j >>= 1) {
      int i = 2 * t - (t & (j - 1));
      int ixj = i ^ j;  // > i since (i & j) == 0
      bool up = ((i & k) == 0);
      float x = a[i], y = a[ixj];
      if ((x > y) == up) { a[i] = y; a[ixj] = x; }
      __syncthreads();
    }
  }
  if (t == 0) {
    float csum = 0.f;
    int cnt = 0;
    for (int j = 0; j < 128; ++j) {
      float ad = a[127 - j];  // descending
      csum += ad;
      float c = csum - KAPPA;
      css[j] = c;
      if (ad * (float)(j + 1) > c) cnt++;
    }
    s_alpha = css[cnt - 1] / (float)cnt;
    s_l1 = csum;
  }
  __syncthreads();
  float alpha = s_alpha;
  bool doproj = (s_l1 > KAPPA);
  for (int idx = t; idx < 128; idx += 64) {
    float w = W[row * 128 + idx];
    float pp = fmaxf(fabsf(w) - alpha, 0.f);
    float res = doproj ? ((w >= 0.f) ? pp : -pp) : w;
    WpT[idx * 128 + row] = res;  // store transposed: WpT[j][f] = Wp[f][j]
  }
}

// ---------- 128x128 transpose (Omega -> OmegaT) ----------
__global__ __launch_bounds__(256) void transpose128(const float* __restrict__ A,
                                                    float* __restrict__ AT) {
  int idx = blockIdx.x * 256 + threadIdx.x;  // < 16384
  int f = idx >> 7, p = idx & 127;
  AT[p * 128 + f] = A[idx];
}

// ---------- CSR build: histogram / scan / scatter ----------
__global__ __launch_bounds__(256) void hist_kernel(const int* __restrict__ col,
                                                   int* __restrict__ counts, int E) {
  int e = blockIdx.x * 256 + threadIdx.x;
  if (e < E) atomicAdd(&counts[col[e]], 1);
}

__global__ __launch_bounds__(1024) void scan_kernel(const int* __restrict__ counts,
                                                    int* __restrict__ offs,
                                                    int* __restrict__ cursors, int N) {
  __shared__ int part[1024];
  int t = threadIdx.x;
  int per = (N + 1023) >> 10;
  int lo = t * per;
  int hi = min(lo + per, N);
  int s = 0;
  for (int i = lo; i < hi; ++i) s += counts[i];
  part[t] = s;
  __syncthreads();
  for (int d = 1; d < 1024; d <<= 1) {
    int v = (t >= d) ? part[t - d] : 0;
    __syncthreads();
    part[t] += v;
    __syncthreads();
  }
  int run = (t > 0) ? part[t - 1] : 0;
  for (int i = lo; i < hi; ++i) {
    offs[i] = run;
    cursors[i] = run;
    run += counts[i];
  }
  if (t == 1023) offs[N] = part[1023];
}

__global__ __launch_bounds__(256) void scatter_kernel(const int* __restrict__ erow,
                                                      const int* __restrict__ ecol,
                                                      const float* __restrict__ eval,
                                                      int* __restrict__ cursors,
                                                      int* __restrict__ crow,
                                                      float* __restrict__ cval, int E) {
  int e = blockIdx.x * 256 + threadIdx.x;
  if (e < E) {
    int c = ecol[e];
    int pos = atomicAdd(&cursors[c], 1);
    crow[pos] = erow[e];
    cval[pos] = eval[e];
  }
}

// ---------- GEMM, feature-major input (U): Out[n][f] = sum_j M[f][j] * In[j][n] ----------
__global__ __launch_bounds__(256) void gemm_fm(const float* __restrict__ In,  // [128][N]
                                               const float* __restrict__ MT,  // MT[j*128+f]
                                               float* __restrict__ Out,       // [N][128]
                                               int N) {
  int tid = threadIdx.x;
  int n = blockIdx.x * 64 + (tid & 63);
  int fg = __builtin_amdgcn_readfirstlane(tid >> 6);  // wave-uniform feature group
  int nc = min(n, N - 1);
  float acc[32];
#pragma unroll
  for (int k = 0; k < 32; ++k) acc[k] = 0.f;
  for (int j = 0; j < 128; ++j) {
    float x = In[(size_t)j * N + nc];           // coalesced across lanes
    const float* wr = MT + j * 128 + fg * 32;   // uniform -> s_load
#pragma unroll
    for (int k = 0; k < 32; ++k) acc[k] = fmaf(wr[k], x, acc[k]);
  }
  if (n < N) {
    float4* o = (float4*)(Out + (size_t)n * 128 + fg * 32);
#pragma unroll
    for (int q = 0; q < 8; ++q)
      o[q] = make_float4(acc[q * 4], acc[q * 4 + 1], acc[q * 4 + 2], acc[q * 4 + 3]);
  }
}

// ---------- GEMM, node-major input (X): Y[n][f] = sum_j M[f][j] * Xt[n][j] ----------
__global__ __launch_bounds__(256) void gemm_nm(const float* __restrict__ Xt,  // [N][128]
                                               const float* __restrict__ MT,
                                               float* __restrict__ Y, int N) {
  __shared__ float Xs[64][129];  // +1 pad: bank (n+j)%32, 2-way = free
  int tid = threadIdx.x;
  int n0 = blockIdx.x * 64;
  const float4* Xg = (const float4*)(Xt + (size_t)n0 * 128);
#pragma unroll
  for (int i = 0; i < 8; ++i) {
    int idx = tid + i * 256;  // 2048 float4s per tile
    int nn = idx >> 5;
    int cc = idx & 31;
    float4 v = make_float4(0.f, 0.f, 0.f, 0.f);
    if (n0 + nn < N) v = Xg[idx];
    float* xr = &Xs[nn][cc * 4];
    xr[0] = v.x; xr[1] = v.y; xr[2] = v.z; xr[3] = v.w;
  }
  __syncthreads();
  int n = tid & 63;
  int fg = __builtin_amdgcn_readfirstlane(tid >> 6);
  float acc[32];
#pragma unroll
  for (int k = 0; k < 32; ++k) acc[k] = 0.f;
  for (int j = 0; j < 128; ++j) {
    float x = Xs[n][j];
    const float* wr = MT + j * 128 + fg * 32;  // uniform -> s_load, SGPR FMA operand
#pragma unroll
    for (int k = 0; k < 32; ++k) acc[k] = fmaf(wr[k], x, acc[k]);
  }
  int node = n0 + n;
  if (node < N) {
    float4* o = (float4*)(Y + (size_t)node * 128 + fg * 32);
#pragma unroll
    for (int q = 0; q < 8; ++q)
      o[q] = make_float4(acc[q * 4], acc[q * 4 + 1], acc[q * 4 + 2], acc[q * 4 + 3]);
  }
}

// ---------- SpMM: Xo[c][:] = (mode ? relu(sum + Bt[c][:]) : sum), sum over CSR[c] of v*Y[row][:]
__global__ __launch_bounds__(256) void spmm_kernel(const float* __restrict__ Y,  // [N][128]
                                                   const int* __restrict__ offs,
                                                   const int* __restrict__ crow,
                                                   const float* __restrict__ cval,
                                                   const float* __restrict__ Bt,
                                                   float* __restrict__ Xo, int N, int mode) {
  int c = blockIdx.x * 4 + (threadIdx.x >> 6);  // one wave per node
  c = __builtin_amdgcn_readfirstlane(c);
  if (c >= N) return;
  int l = threadIdx.x & 63;
  int beg = offs[c], end = offs[c + 1];
  float ax = 0.f, ay = 0.f;
  for (int e = beg; e < end; ++e) {   // e wave-uniform -> scalar loads
    int r = crow[e];
    float v = cval[e];
    const float2 y = *(const float2*)(Y + (size_t)r * 128 + l * 2);  // 512B/wave coalesced
    ax = fmaf(v, y.x, ax);
    ay = fmaf(v, y.y, ay);
  }
  size_t oi = (size_t)c * 128 + l * 2;
  if (mode) {
    const float2 b = *(const float2*)(Bt + oi);
    ax = fmaxf(ax + b.x, 0.f);
    ay = fmaxf(ay + b.y, 0.f);
  }
  *(float2*)(Xo + oi) = make_float2(ax, ay);
}

// ---------- final transpose: node-major [N][128] -> feature-major [128][N] ----------
__global__ __launch_bounds__(256) void transpose_out(const float* __restrict__ Zt,
                                                     float* __restrict__ out, int N) {
  __shared__ float Ts[64][129];
  int tid = threadIdx.x;
  int n0 = blockIdx.x * 64;
  const float4* Zg = (const float4*)(Zt + (size_t)n0 * 128);
#pragma unroll
  for (int i = 0; i < 8; ++i) {
    int idx = tid + i * 256;
    int nn = idx >> 5, cc = idx & 31;
    float4 v = make_float4(0.f, 0.f, 0.f, 0.f);
    if (n0 + nn < N) v = Zg[idx];
    float* xr = &Ts[nn][cc * 4];
    xr[0] = v.x; xr[1] = v.y; xr[2] = v.z; xr[3] = v.w;
  }
  __syncthreads();
  int l = tid & 63, w = tid >> 6;
  int n = n0 + l;
  if (n < N) {
    for (int f = w; f < 128; f += 4)
      out[(size_t)f * N + n] = Ts[l][f];  // 256B coalesced stores per wave
  }
}

extern "C" void kernel_launch(void* const* d_in, const int* in_sizes, int n_in,
                              void* d_out, int out_size, void* d_ws, size_t ws_size,
                              hipStream_t stream) {
  const float* W     = (const float*)d_in[0];
  const float* Om    = (const float*)d_in[1];
  const float* U     = (const float*)d_in[2];
  const float* evalp = (const float*)d_in[3];
  const int*   erow  = (const int*)d_in[4];
  const int*   ecol  = (const int*)d_in[5];
  // fw_mitr (d_in[6]) is 50 per problem spec; fixed 50+1 steps (contraction => safe).

  int N = in_sizes[2] / 128;
  int E = in_sizes[3];

  char* p = (char*)d_ws;
  auto alloc = [&](size_t bytes) {
    char* r = p;
    p += (bytes + 255) & ~(size_t)255;
    return r;
  };
  float* WpT   = (float*)alloc(128 * 128 * 4);
  float* OmT   = (float*)alloc(128 * 128 * 4);
  int* counts  = (int*)alloc((size_t)(N + 1) * 4);
  int* offs    = (int*)alloc((size_t)(N + 1) * 4);
  int* cursors = (int*)alloc((size_t)N * 4);
  int* crow    = (int*)alloc((size_t)E * 4);
  float* cval  = (float*)alloc((size_t)E * 4);
  float* Bt    = (float*)alloc((size_t)N * 128 * 4);
  float* Xa    = (float*)alloc((size_t)N * 128 * 4);
  float* Xb    = (float*)alloc((size_t)N * 128 * 4);
  float* out   = (float*)d_out;
  float* Y     = out;  // d_out doubles as GEMM-output scratch

  (void)hipMemsetAsync(counts, 0, (size_t)(N + 1) * 4, stream);
  proj_kernel<<<128, 64, 0, stream>>>(W, WpT);
  transpose128<<<64, 256, 0, stream>>>(Om, OmT);
  int ebl = (E + 255) / 256;
  hist_kernel<<<ebl, 256, 0, stream>>>(ecol, counts, E);
  scan_kernel<<<1, 1024, 0, stream>>>(counts, offs, cursors, N);
  scatter_kernel<<<ebl, 256, 0, stream>>>(erow, ecol, evalp, cursors, crow, cval, E);

  int gbl = (N + 63) / 64;
  int sbl = (N + 3) / 4;
  // Vt = (Omega @ U)^T into Xb, then Bt = A^T-gather of Vt
  gemm_fm<<<gbl, 256, 0, stream>>>(U, OmT, Xb, N);
  spmm_kernel<<<sbl, 256, 0, stream>>>(Xb, offs, crow, cval, (const float*)nullptr, Bt, N, 0);

  // X_0 = B; 50 loop iterations + 1 final pass, all identical: X <- relu(gather(Wp@X) + B)
  const float* Xin = Bt;
  float* Xout = Xa;
  for (int it = 0; it < 51; ++it) {
    gemm_nm<<<gbl, 256, 0, stream>>>(Xin, WpT, Y, N);
    spmm_kernel<<<sbl, 256, 0, stream>>>(Y, offs, crow, cval, Bt, Xout, N, 1);
    Xin = Xout;
    Xout = (Xout == Xa) ? Xb : Xa;
  }
  transpose_out<<<gbl, 256, 0, stream>>>(Xin, out, N);
}

// Round 3
// 1864.074 us; speedup vs baseline: 2.9463x; 2.9463x over previous
//
#include <hip/hip_runtime.h>

#define KAPPA 0.99f
#define TOL_F 3e-6f

// ---------- Projection of each row of W onto the L1 ball of radius KAPPA ----------
__global__ __launch_bounds__(64) void proj_kernel(const float* __restrict__ W,
                                                  float* __restrict__ WpT) {
  __shared__ float a[128];
  __shared__ float css[128];
  __shared__ float s_alpha, s_l1;
  int row = blockIdx.x;
  int t = threadIdx.x;
  a[t]      = fabsf(W[row * 128 + t]);
  a[t + 64] = fabsf(W[row * 128 + t + 64]);
  __syncthreads();
  for (int k = 2; k <= 128; k <<= 1) {
    for (int j = k >> 1; j > 0; j >>= 1) {
      int i = 2 * t - (t & (j - 1));
      int ixj = i ^ j;
      bool up = ((i & k) == 0);
      float x = a[i], y = a[ixj];
      if ((x > y) == up) { a[i] = y; a[ixj] = x; }
      __syncthreads();
    }
  }
  if (t == 0) {
    float csum = 0.f;
    int cnt = 0;
    for (int j = 0; j < 128; ++j) {
      float ad = a[127 - j];
      csum += ad;
      float c = csum - KAPPA;
      css[j] = c;
      if (ad * (float)(j + 1) > c) cnt++;
    }
    s_alpha = css[cnt - 1] / (float)cnt;
    s_l1 = csum;
  }
  __syncthreads();
  float alpha = s_alpha;
  bool doproj = (s_l1 > KAPPA);
  for (int idx = t; idx < 128; idx += 64) {
    float w = W[row * 128 + idx];
    float pp = fmaxf(fabsf(w) - alpha, 0.f);
    float res = doproj ? ((w >= 0.f) ? pp : -pp) : w;
    WpT[idx * 128 + row] = res;
  }
}

// ---------- 128x128 transpose ----------
__global__ __launch_bounds__(256) void transpose128(const float* __restrict__ A,
                                                    float* __restrict__ AT) {
  int idx = blockIdx.x * 256 + threadIdx.x;
  int f = idx >> 7, p = idx & 127;
  AT[p * 128 + f] = A[idx];
}

// ---------- CSR build ----------
__global__ __launch_bounds__(256) void hist_kernel(const int* __restrict__ col,
                                                   int* __restrict__ counts, int E) {
  int e = blockIdx.x * 256 + threadIdx.x;
  if (e < E) atomicAdd(&counts[col[e]], 1);
}

// 3-phase scan: A = per-256-block exclusive scan, B = scan of block sums, C = add base
__global__ __launch_bounds__(256) void scanA(const int* __restrict__ counts,
                                             int* __restrict__ offs,
                                             int* __restrict__ bsums, int N) {
  __shared__ int tmp[256];
  int t = threadIdx.x, i = blockIdx.x * 256 + t;
  int v = (i < N) ? counts[i] : 0;
  tmp[t] = v;
  __syncthreads();
  for (int d = 1; d < 256; d <<= 1) {
    int u = (t >= d) ? tmp[t - d] : 0;
    __syncthreads();
    tmp[t] += u;
    __syncthreads();
  }
  if (i < N) offs[i] = tmp[t] - v;  // local exclusive
  if (t == 255) bsums[blockIdx.x] = tmp[255];
}

__global__ __launch_bounds__(256) void scanB(int* __restrict__ bsums, int nb) {
  __shared__ int tmp[256];
  int t = threadIdx.x;
  int v = (t < nb) ? bsums[t] : 0;
  tmp[t] = v;
  __syncthreads();
  for (int d = 1; d < 256; d <<= 1) {
    int u = (t >= d) ? tmp[t - d] : 0;
    __syncthreads();
    tmp[t] += u;
    __syncthreads();
  }
  if (t < nb) bsums[t] = tmp[t] - v;  // exclusive base per block
}

__global__ __launch_bounds__(256) void scanC(int* __restrict__ offs,
                                             const int* __restrict__ bsums,
                                             int* __restrict__ cursors, int N, int E) {
  int i = blockIdx.x * 256 + threadIdx.x;
  if (i < N) {
    int o = offs[i] + bsums[blockIdx.x];
    offs[i] = o;
    cursors[i] = o;
  }
  if (i == 0) offs[N] = E;
}

__global__ __launch_bounds__(256) void scatter_kernel(const int* __restrict__ erow,
                                                      const int* __restrict__ ecol,
                                                      const float* __restrict__ eval,
                                                      int* __restrict__ cursors,
                                                      int* __restrict__ crow,
                                                      float* __restrict__ cval, int E) {
  int e = blockIdx.x * 256 + threadIdx.x;
  if (e < E) {
    int c = ecol[e];
    int pos = atomicAdd(&cursors[c], 1);
    crow[pos] = erow[e];
    cval[pos] = eval[e];
  }
}

// ---------- GEMM, feature-major input (U) ----------
__global__ __launch_bounds__(256) void gemm_fm(const float* __restrict__ In,
                                               const float* __restrict__ MT,
                                               float* __restrict__ Out, int N) {
  int tid = threadIdx.x;
  int n = blockIdx.x * 64 + (tid & 63);
  int fg = __builtin_amdgcn_readfirstlane(tid >> 6);
  int nc = min(n, N - 1);
  float acc[32];
#pragma unroll
  for (int k = 0; k < 32; ++k) acc[k] = 0.f;
  for (int j = 0; j < 128; ++j) {
    float x = In[(size_t)j * N + nc];
    const float* wr = MT + j * 128 + fg * 32;
#pragma unroll
    for (int k = 0; k < 32; ++k) acc[k] = fmaf(wr[k], x, acc[k]);
  }
  if (n < N) {
    float4* o = (float4*)(Out + (size_t)n * 128 + fg * 32);
#pragma unroll
    for (int q = 0; q < 8; ++q)
      o[q] = make_float4(acc[q * 4], acc[q * 4 + 1], acc[q * 4 + 2], acc[q * 4 + 3]);
  }
}

// ---------- GEMM, node-major input (X), with convergence skip ----------
__global__ __launch_bounds__(256) void gemm_nm(const float* __restrict__ Xt,
                                               const float* __restrict__ MT,
                                               float* __restrict__ Y, int N,
                                               const float* __restrict__ errp) {
  if (errp && *errp < TOL_F) return;  // previous iteration converged -> no-op
  __shared__ float Xs[64][129];
  int tid = threadIdx.x;
  int n0 = blockIdx.x * 64;
  const float4* Xg = (const float4*)(Xt + (size_t)n0 * 128);
#pragma unroll
  for (int i = 0; i < 8; ++i) {
    int idx = tid + i * 256;
    int nn = idx >> 5, cc = idx & 31;
    float4 v = make_float4(0.f, 0.f, 0.f, 0.f);
    if (n0 + nn < N) v = Xg[idx];
    float* xr = &Xs[nn][cc * 4];
    xr[0] = v.x; xr[1] = v.y; xr[2] = v.z; xr[3] = v.w;
  }
  __syncthreads();
  int n = tid & 63;
  int fg = __builtin_amdgcn_readfirstlane(tid >> 6);
  float acc[32];
#pragma unroll
  for (int k = 0; k < 32; ++k) acc[k] = 0.f;
  for (int j = 0; j < 128; ++j) {
    float x = Xs[n][j];
    const float* wr = MT + j * 128 + fg * 32;
#pragma unroll
    for (int k = 0; k < 32; ++k) acc[k] = fmaf(wr[k], x, acc[k]);
  }
  int node = n0 + n;
  if (node < N) {
    float4* o = (float4*)(Y + (size_t)node * 128 + fg * 32);
#pragma unroll
    for (int q = 0; q < 8; ++q)
      o[q] = make_float4(acc[q * 4], acc[q * 4 + 1], acc[q * 4 + 2], acc[q * 4 + 3]);
  }
}

// ---------- SpMM with optional bias+relu, convergence skip, and err reduce ----------
__global__ __launch_bounds__(256) void spmm_kernel(const float* __restrict__ Y,
                                                   const int* __restrict__ offs,
                                                   const int* __restrict__ crow,
                                                   const float* __restrict__ cval,
                                                   const float* __restrict__ Bt,
                                                   float* __restrict__ Xo,
                                                   float* __restrict__ Xo2,  // optional dup store
                                                   int N, int mode,
                                                   const float* __restrict__ errp,
                                                   unsigned* __restrict__ err_out) {
  if (errp && *errp < TOL_F) return;  // uniform across block: safe before barriers
  int c = blockIdx.x * 4 + (threadIdx.x >> 6);
  c = __builtin_amdgcn_readfirstlane(c);
  bool active = (c < N);
  int l = threadIdx.x & 63;
  float m = 0.f;
  if (active) {
    int beg = offs[c], end = offs[c + 1];
    float ax = 0.f, ay = 0.f;
    for (int e = beg; e < end; ++e) {  // e wave-uniform -> scalar loads
      int r = crow[e];
      float v = cval[e];
      const float2 y = *(const float2*)(Y + (size_t)r * 128 + l * 2);
      ax = fmaf(v, y.x, ax);
      ay = fmaf(v, y.y, ay);
    }
    size_t oi = (size_t)c * 128 + l * 2;
    if (mode) {
      const float2 b = *(const float2*)(Bt + oi);
      ax = fmaxf(ax + b.x, 0.f);
      ay = fmaxf(ay + b.y, 0.f);
      if (err_out) {
        const float2 old = *(const float2*)(Xo + oi);  // in-place: old X value
        m = fmaxf(fabsf(ax - old.x), fabsf(ay - old.y));
      }
    }
    *(float2*)(Xo + oi) = make_float2(ax, ay);
    if (Xo2) *(float2*)(Xo2 + oi) = make_float2(ax, ay);
  }
  if (err_out) {
    // wave reduce then block reduce -> one atomic per block
#pragma unroll
    for (int o = 32; o > 0; o >>= 1) m = fmaxf(m, __shfl_xor(m, o, 64));
    __shared__ float werr[4];
    if (l == 0) werr[threadIdx.x >> 6] = m;
    __syncthreads();
    if (threadIdx.x == 0) {
      float bm = fmaxf(fmaxf(werr[0], werr[1]), fmaxf(werr[2], werr[3]));
      atomicMax(err_out, __float_as_uint(bm));  // nonneg floats: uint-monotone
    }
  }
}

// ---------- final transpose: node-major [N][128] -> feature-major [128][N] ----------
__global__ __launch_bounds__(256) void transpose_out(const float* __restrict__ Zt,
                                                     float* __restrict__ out, int N) {
  __shared__ float Ts[64][129];
  int tid = threadIdx.x;
  int n0 = blockIdx.x * 64;
  const float4* Zg = (const float4*)(Zt + (size_t)n0 * 128);
#pragma unroll
  for (int i = 0; i < 8; ++i) {
    int idx = tid + i * 256;
    int nn = idx >> 5, cc = idx & 31;
    float4 v = make_float4(0.f, 0.f, 0.f, 0.f);
    if (n0 + nn < N) v = Zg[idx];
    float* xr = &Ts[nn][cc * 4];
    xr[0] = v.x; xr[1] = v.y; xr[2] = v.z; xr[3] = v.w;
  }
  __syncthreads();
  int l = tid & 63, w = tid >> 6;
  int n = n0 + l;
  if (n < N) {
    for (int f = w; f < 128; f += 4)
      out[(size_t)f * N + n] = Ts[l][f];
  }
}

extern "C" void kernel_launch(void* const* d_in, const int* in_sizes, int n_in,
                              void* d_out, int out_size, void* d_ws, size_t ws_size,
                              hipStream_t stream) {
  const float* W     = (const float*)d_in[0];
  const float* Om    = (const float*)d_in[1];
  const float* U     = (const float*)d_in[2];
  const float* evalp = (const float*)d_in[3];
  const int*   erow  = (const int*)d_in[4];
  const int*   ecol  = (const int*)d_in[5];

  int N = in_sizes[2] / 128;
  int E = in_sizes[3];

  char* p = (char*)d_ws;
  auto alloc = [&](size_t bytes) {
    char* r = p;
    p += (bytes + 255) & ~(size_t)255;
    return r;
  };
  float* WpT   = (float*)alloc(128 * 128 * 4);
  float* OmT   = (float*)alloc(128 * 128 * 4);
  int* counts  = (int*)alloc((size_t)(N + 1) * 4);
  int* offs    = (int*)alloc((size_t)(N + 1) * 4);
  int* cursors = (int*)alloc((size_t)N * 4);
  int* bsums   = (int*)alloc(1024 * 4);
  float* errs  = (float*)alloc(64 * 4);  // errs[t] = max|X_t - X_{t-1}|
  int* crow    = (int*)alloc((size_t)E * 4);
  float* cval  = (float*)alloc((size_t)E * 4);
  float* Bt    = (float*)alloc((size_t)N * 128 * 4);
  float* X     = (float*)alloc((size_t)N * 128 * 4);
  float* out   = (float*)d_out;
  float* Y     = out;  // d_out doubles as GEMM-output scratch

  (void)hipMemsetAsync(counts, 0, (size_t)(N + 1) * 4, stream);
  (void)hipMemsetAsync(errs, 0, 64 * 4, stream);      // skipped iters read 0 -> stay skipped
  (void)hipMemsetAsync(errs, 0x7F, 4, stream);        // errs[0] = 3.4e38 -> iter 1 runs

  proj_kernel<<<128, 64, 0, stream>>>(W, WpT);
  transpose128<<<64, 256, 0, stream>>>(Om, OmT);
  int ebl = (E + 255) / 256;
  int nbl = (N + 255) / 256;  // 196 <= 256 (scanB single-block capacity)
  hist_kernel<<<ebl, 256, 0, stream>>>(ecol, counts, E);
  scanA<<<nbl, 256, 0, stream>>>(counts, offs, bsums, N);
  scanB<<<1, 256, 0, stream>>>(bsums, nbl);
  scanC<<<nbl, 256, 0, stream>>>(offs, bsums, cursors, N, E);
  scatter_kernel<<<ebl, 256, 0, stream>>>(erow, ecol, evalp, cursors, crow, cval, E);

  int gbl = (N + 63) / 64;
  int sbl = (N + 3) / 4;
  // B = gather(Omega@U); also seed X = B (X_0 = B)
  gemm_fm<<<gbl, 256, 0, stream>>>(U, OmT, Y, N);
  spmm_kernel<<<sbl, 256, 0, stream>>>(Y, offs, crow, cval, (const float*)nullptr,
                                       Bt, X, N, 0, (const float*)nullptr, (unsigned*)nullptr);

  // body iterations 1..50, in-place X, skip once errs[t-1] < TOL
  for (int it = 1; it <= 50; ++it) {
    gemm_nm<<<gbl, 256, 0, stream>>>(X, WpT, Y, N, errs + (it - 1));
    spmm_kernel<<<sbl, 256, 0, stream>>>(Y, offs, crow, cval, Bt, X, (float*)nullptr,
                                         N, 1, errs + (it - 1), (unsigned*)(errs + it));
  }
  // final recompute pass (always runs, matches reference's compute_dphi)
  gemm_nm<<<gbl, 256, 0, stream>>>(X, WpT, Y, N, (const float*)nullptr);
  spmm_kernel<<<sbl, 256, 0, stream>>>(Y, offs, crow, cval, Bt, X, (float*)nullptr,
                                       N, 1, (const float*)nullptr, (unsigned*)nullptr);
  transpose_out<<<gbl, 256, 0, stream>>>(X, out, N);
}